// Round 9
// baseline (331.764 us; speedup 1.0000x reference)
//
#include <hip/hip_runtime.h>

// PPAModel: node encoder -> edge gather/concat -> edge MLP -> sigmoid
// IN=128, HID=256, OUT=128, N_NODES=100000, N_EDGES=1000000
//
// v9 (v8 factorization, tuned):
//   e@W3 = h_src@W3t + h_dst@W3b ;  h = relu1@W2
//   prep:   Wut=W2@W3t, Wvt=W2@W3b (bf16-swizzled directly), bu,bv
//   node_uv: U = relu1@Wut + bu, V = relu1@Wvt + bv   (per node, bf16)
//   edge_pred: out = sigmoid( relu(U[src]+V[dst]) . W4 + b4 )
// r9 changes: edge_pred grid 1024->2048 (32 waves/CU; was occupancy-capped
// at 42%), prep2 folded into prep1, node_uv non-persistent 1563 blocks at
// 3 blocks/CU with L2-streamed B-fragments (node MFMA is tiny; overlap
// across blocks beats register-hoarding).
//
// ws layout (~103.5 MB):
//   flag @ 0          w1s @ 256 (64KB)
//   wuts @ 65792 (128KB)   wvts @ 196864 (128KB)
//   bu @ 327936 (1KB)      bv @ 328960 (1KB)
//   U @ 1048576 (51.2MB)   V @ 52248576 (51.2MB)

#define NN 100000
#define NE 1000000
#define NTN 1563
#define GRID_EP 2048

typedef __attribute__((ext_vector_type(8))) __bf16 bf16x8;
typedef __attribute__((ext_vector_type(4))) float f32x4;
typedef __attribute__((ext_vector_type(4))) unsigned short us4;

__device__ __forceinline__ unsigned short f2bf(float f) {
    unsigned u = __float_as_uint(f);
    return (unsigned short)((u + 0x7FFFu + ((u >> 16) & 1u)) >> 16);
}
__device__ __forceinline__ float bflo(unsigned w) {
    return __uint_as_float(w << 16);
}
__device__ __forceinline__ float bfhi(unsigned w) {
    return __uint_as_float(w & 0xffff0000u);
}

template <int CTRL>
__device__ __forceinline__ float dpp_add(float v) {
    return v + __int_as_float(__builtin_amdgcn_update_dpp(
                   0, __float_as_int(v), CTRL, 0xF, 0xF, true));
}
// sum over 16 lanes of a DPP row; valid at (lane&15)==15 (row_shr -> high lane)
__device__ __forceinline__ float row_reduce16(float v) {
    v = dpp_add<0x118>(v);
    v = dpp_add<0x114>(v);
    v = dpp_add<0x112>(v);
    v = dpp_add<0x111>(v);
    return v;
}

// ---------------- prep: W1 swizzle, Wut/Wvt bf16-swizzled, bu/bv, flag ----
__global__ void prep1(const float* __restrict__ W1, const float* __restrict__ W2,
                      const float* __restrict__ W3, const float* __restrict__ b2,
                      const float* __restrict__ b3, const void* __restrict__ eidx,
                      unsigned short* __restrict__ w1s,
                      unsigned short* __restrict__ wuts,
                      unsigned short* __restrict__ wvts, float* __restrict__ bu,
                      float* __restrict__ bv, int* __restrict__ flag) {
    int t = blockIdx.x * blockDim.x + threadIdx.x;  // 131072 threads
    if (t < 32768) {  // W1 swizzle: K=128, N=256, [k/8][n][k%8]
        int k = t >> 8, n = t & 255;
        w1s[(k >> 3) * 2048 + n * 8 + (k & 7)] = f2bf(W1[t]);
    }
    if (t < 65536) {  // Wut[k][n] = sum_j W2[k][j] * W3[j][n], j<128
        int k = t >> 8, n = t & 255;
        float s = 0.0f;
        for (int j = 0; j < 128; ++j) s += W2[k * 128 + j] * W3[j * 256 + n];
        wuts[(k >> 3) * 2048 + n * 8 + (k & 7)] = f2bf(s);
    } else {          // Wvt[k][n] = sum_j W2[k][j] * W3[128+j][n]
        int i = t - 65536;
        int k = i >> 8, n = i & 255;
        float s = 0.0f;
        for (int j = 0; j < 128; ++j) s += W2[k * 128 + j] * W3[(128 + j) * 256 + n];
        wvts[(k >> 3) * 2048 + n * 8 + (k & 7)] = f2bf(s);
    }
    if (t < 256) {    // bu = b3 + b2 @ W3t
        float s = b3[t];
        for (int j = 0; j < 128; ++j) s += b2[j] * W3[j * 256 + t];
        bu[t] = s;
    } else if (t < 512) {  // bv = b2 @ W3b
        int n = t - 256;
        float s = 0.0f;
        for (int j = 0; j < 128; ++j) s += b2[j] * W3[(128 + j) * 256 + n];
        bv[n] = s;
    }
    if (t == 0) {
        const unsigned* u = (const unsigned*)eidx;
        int all0 = 1;
        for (int i = 0; i < 32; ++i) all0 &= (u[2 * i + 1] == 0u);
        *flag = all0;
    }
}

// ---------------- node_uv: x -> relu1 -> U,V; 1563 blocks, 4 waves --------
__global__ __launch_bounds__(256, 3) void node_uv(
    const float* __restrict__ x, const float* __restrict__ b1,
    const unsigned short* __restrict__ w1s, const unsigned short* __restrict__ wuts,
    const unsigned short* __restrict__ wvts, const float* __restrict__ bu,
    const float* __restrict__ bv, unsigned short* __restrict__ Ug,
    unsigned short* __restrict__ Vg) {
    __shared__ __align__(16) unsigned short A1[64 * 136];  // 17408 B
    __shared__ __align__(16) unsigned short A2[64 * 264];  // 33792 B

    const int t = threadIdx.x, lane = t & 63, w = t >> 6;  // w: 0..3
    const int cl = lane & 15, q = lane >> 4;
    const int nb = w * 64;   // this wave's 64 N-cols
    const int m0 = blockIdx.x * 64;

    // stage x -> A1 bf16
    {
        const float4* x4 = (const float4*)x;
#pragma unroll
        for (int i = 0; i < 8; ++i) {
            int lin = i * 256 + t;
            int m = lin >> 5, c = lin & 31;
            int node = m0 + m;
            if (node > NN - 1) node = NN - 1;
            float4 v = x4[node * 32 + c];
            us4 b;
            b.x = f2bf(v.x); b.y = f2bf(v.y); b.z = f2bf(v.z); b.w = f2bf(v.w);
            *(us4*)(A1 + m * 136 + c * 4) = b;
        }
    }
    float b1v[4], buv[4], bvv[4];
#pragma unroll
    for (int nt = 0; nt < 4; ++nt) {
        int n = nb + nt * 16 + cl;
        b1v[nt] = b1[n];
        buv[nt] = bu[n];
        bvv[nt] = bv[n];
    }
    __syncthreads();

    // GEMM1: [64x128]x[128x256], B streamed from L2
    {
        f32x4 acc[4][4];
#pragma unroll
        for (int mt = 0; mt < 4; ++mt)
#pragma unroll
            for (int nt = 0; nt < 4; ++nt)
                acc[mt][nt] = (f32x4){b1v[nt], b1v[nt], b1v[nt], b1v[nt]};
#pragma unroll
        for (int s = 0; s < 4; ++s) {
            bf16x8 a[4], bw[4];
#pragma unroll
            for (int mt = 0; mt < 4; ++mt)
                a[mt] = *(const bf16x8*)(A1 + (mt * 16 + cl) * 136 + s * 32 + q * 8);
#pragma unroll
            for (int nt = 0; nt < 4; ++nt)
                bw[nt] = *(const bf16x8*)(w1s + (s * 4 + q) * 2048 +
                                          (nb + nt * 16 + cl) * 8);
#pragma unroll
            for (int mt = 0; mt < 4; ++mt)
#pragma unroll
                for (int nt = 0; nt < 4; ++nt)
                    acc[mt][nt] = __builtin_amdgcn_mfma_f32_16x16x32_bf16(
                        a[mt], bw[nt], acc[mt][nt], 0, 0, 0);
        }
        // relu -> A2
#pragma unroll
        for (int mt = 0; mt < 4; ++mt)
#pragma unroll
            for (int nt = 0; nt < 4; ++nt)
#pragma unroll
                for (int r = 0; r < 4; ++r) {
                    float v = fmaxf(acc[mt][nt][r], 0.0f);
                    A2[(mt * 16 + q * 4 + r) * 264 + nb + nt * 16 + cl] = f2bf(v);
                }
    }
    __syncthreads();

    // GEMM U: [64x256]x[256x256], B streamed; then GEMM V (A2 reused, no sync)
#pragma unroll
    for (int pass = 0; pass < 2; ++pass) {
        const unsigned short* wt = pass ? wvts : wuts;
        unsigned short* outg = pass ? Vg : Ug;
        f32x4 acc[4][4];
#pragma unroll
        for (int mt = 0; mt < 4; ++mt)
#pragma unroll
            for (int nt = 0; nt < 4; ++nt) {
                float bb = pass ? bvv[nt] : buv[nt];
                acc[mt][nt] = (f32x4){bb, bb, bb, bb};
            }
#pragma unroll
        for (int s = 0; s < 8; ++s) {
            bf16x8 a[4], bw[4];
#pragma unroll
            for (int mt = 0; mt < 4; ++mt)
                a[mt] = *(const bf16x8*)(A2 + (mt * 16 + cl) * 264 + s * 32 + q * 8);
#pragma unroll
            for (int nt = 0; nt < 4; ++nt)
                bw[nt] = *(const bf16x8*)(wt + (s * 4 + q) * 2048 +
                                          (nb + nt * 16 + cl) * 8);
#pragma unroll
            for (int mt = 0; mt < 4; ++mt)
#pragma unroll
                for (int nt = 0; nt < 4; ++nt)
                    acc[mt][nt] = __builtin_amdgcn_mfma_f32_16x16x32_bf16(
                        a[mt], bw[nt], acc[mt][nt], 0, 0, 0);
        }
#pragma unroll
        for (int mt = 0; mt < 4; ++mt)
#pragma unroll
            for (int nt = 0; nt < 4; ++nt)
#pragma unroll
                for (int r = 0; r < 4; ++r) {
                    int node = m0 + mt * 16 + q * 4 + r;
                    if (node < NN)
                        outg[node * 256 + nb + nt * 16 + cl] = f2bf(acc[mt][nt][r]);
                }
    }
}

// ---------------- edge_pred: streaming gather + VALU, 32 waves/CU ---------
#define TERM(uw, vw, wa, wb)                                     \
    (fmaxf(bflo(uw) + bflo(vw), 0.0f) * (wa) +                   \
     fmaxf(bfhi(uw) + bfhi(vw), 0.0f) * (wb))

__global__ __launch_bounds__(256, 8) void edge_pred(
    const void* __restrict__ eidx, const unsigned short* __restrict__ Ut,
    const unsigned short* __restrict__ Vt, const float* __restrict__ W4,
    const float* __restrict__ b4, const int* __restrict__ flag,
    float* __restrict__ out) {
    const int t = threadIdx.x, lane = t & 63;
    const int cl = lane & 15, g = lane >> 4;   // 4 edge-groups of 16 lanes
    const int gwid = (blockIdx.x * 256 + t) >> 6;
    const int nw = (GRID_EP * 256) >> 6;
    const bool i64f = (*flag != 0);
    const int* ei32 = (const int*)eidx;
    const long long* ei64 = (const long long*)eidx;

    float w4a[8], w4b[8];
#pragma unroll
    for (int j = 0; j < 8; ++j) {
        w4a[j] = W4[cl * 8 + j];
        w4b[j] = W4[128 + cl * 8 + j];
    }
    const float b4v = b4[0];

    for (int base = gwid * 8; base < NE; base += nw * 8) {
        const int eA = base + g, eB = base + 4 + g;
        int sA = i64f ? (int)ei64[eA] : ei32[eA];
        int dA = i64f ? (int)ei64[NE + eA] : ei32[NE + eA];
        int sB = i64f ? (int)ei64[eB] : ei32[eB];
        int dB = i64f ? (int)ei64[NE + eB] : ei32[NE + eB];
        sA = sA < 0 ? 0 : (sA > NN - 1 ? NN - 1 : sA);
        dA = dA < 0 ? 0 : (dA > NN - 1 ? NN - 1 : dA);
        sB = sB < 0 ? 0 : (sB > NN - 1 ? NN - 1 : sB);
        dB = dB < 0 ? 0 : (dB > NN - 1 ? NN - 1 : dB);

        const uint4* ua = (const uint4*)(Ut + (long)sA * 256) + cl;
        const uint4* va = (const uint4*)(Vt + (long)dA * 256) + cl;
        const uint4* ub = (const uint4*)(Ut + (long)sB * 256) + cl;
        const uint4* vb = (const uint4*)(Vt + (long)dB * 256) + cl;
        uint4 ua0 = ua[0], ua1 = ua[16];
        uint4 va0 = va[0], va1 = va[16];
        uint4 ub0 = ub[0], ub1 = ub[16];
        uint4 vb0 = vb[0], vb1 = vb[16];

        float accA =
            TERM(ua0.x, va0.x, w4a[0], w4a[1]) + TERM(ua0.y, va0.y, w4a[2], w4a[3]) +
            TERM(ua0.z, va0.z, w4a[4], w4a[5]) + TERM(ua0.w, va0.w, w4a[6], w4a[7]) +
            TERM(ua1.x, va1.x, w4b[0], w4b[1]) + TERM(ua1.y, va1.y, w4b[2], w4b[3]) +
            TERM(ua1.z, va1.z, w4b[4], w4b[5]) + TERM(ua1.w, va1.w, w4b[6], w4b[7]);
        float accB =
            TERM(ub0.x, vb0.x, w4a[0], w4a[1]) + TERM(ub0.y, vb0.y, w4a[2], w4a[3]) +
            TERM(ub0.z, vb0.z, w4a[4], w4a[5]) + TERM(ub0.w, vb0.w, w4a[6], w4a[7]) +
            TERM(ub1.x, vb1.x, w4b[0], w4b[1]) + TERM(ub1.y, vb1.y, w4b[2], w4b[3]) +
            TERM(ub1.z, vb1.z, w4b[4], w4b[5]) + TERM(ub1.w, vb1.w, w4b[6], w4b[7]);

        accA = row_reduce16(accA);
        accB = row_reduce16(accB);
        if (cl == 15) {
            out[eA] = 1.0f / (1.0f + __expf(-(accA + b4v)));
            out[eB] = 1.0f / (1.0f + __expf(-(accB + b4v)));
        }
    }
}

extern "C" void kernel_launch(void* const* d_in, const int* in_sizes, int n_in,
                              void* d_out, int out_size, void* d_ws, size_t ws_size,
                              hipStream_t stream) {
    const float* x  = (const float*)d_in[0];
    const void*  ei = d_in[1];
    const float* W1 = (const float*)d_in[2];
    const float* b1 = (const float*)d_in[3];
    const float* W2 = (const float*)d_in[4];
    const float* b2 = (const float*)d_in[5];
    const float* W3 = (const float*)d_in[6];
    const float* b3 = (const float*)d_in[7];
    const float* W4 = (const float*)d_in[8];
    const float* b4 = (const float*)d_in[9];

    char* ws = (char*)d_ws;
    int* flag            = (int*)ws;
    unsigned short* w1s  = (unsigned short*)(ws + 256);
    unsigned short* wuts = (unsigned short*)(ws + 65792);
    unsigned short* wvts = (unsigned short*)(ws + 196864);
    float* bu            = (float*)(ws + 327936);
    float* bv            = (float*)(ws + 328960);
    unsigned short* Ug   = (unsigned short*)(ws + 1048576);
    unsigned short* Vg   = (unsigned short*)(ws + 52248576);

    prep1<<<512, 256, 0, stream>>>(W1, W2, W3, b2, b3, ei, w1s, wuts, wvts, bu, bv, flag);
    node_uv<<<NTN, 256, 0, stream>>>(x, b1, w1s, wuts, wvts, bu, bv, Ug, Vg);
    edge_pred<<<GRID_EP, 256, 0, stream>>>(ei, Ug, Vg, W4, b4, flag, (float*)d_out);
}

// Round 10
// 296.819 us; speedup vs baseline: 1.1177x; 1.1177x over previous
//
#include <hip/hip_runtime.h>

// PPAModel: node encoder -> edge gather/concat -> edge MLP -> sigmoid
// IN=128, HID=256, OUT=128, N_NODES=100000, N_EDGES=1000000
//
// v10 (v9 + coalesced U/V epilogue):
//   e@W3 = h_src@W3t + h_dst@W3b ;  h = relu1@W2
//   prep:   Wut=W2@W3t, Wvt=W2@W3b (bf16-swizzled), bu,bv, w4p (permuted W4)
//   node_uv: U = relu1@Wut + bu, V = relu1@Wvt + bv  -> PERMUTED row layout:
//            phys p = nb + cl*4 + nt  <->  hidden = nb + nt*16 + cl
//            (edge_pred only dots rows with W4, so intra-row order is free;
//             permuting makes the MFMA C-layout epilogue a ushort4 store:
//             8 B/lane, 4x128 B segments vs r9's 4x32 B scalar stores --
//             the node phase was store-pipe-bound at ~0.6 TB/s)
//   edge_pred: out = sigmoid( relu(U[src]+V[dst]) . w4p + b4 )
//
// ws layout (~103.5 MB):
//   flag @ 0          w1s @ 256 (64KB)
//   wuts @ 65792 (128KB)   wvts @ 196864 (128KB)
//   bu @ 327936 (1KB)      bv @ 328960 (1KB)    w4p @ 329984 (1KB)
//   U @ 1048576 (51.2MB)   V @ 52248576 (51.2MB)

#define NN 100000
#define NE 1000000
#define NTN 1563
#define GRID_EP 2048

typedef __attribute__((ext_vector_type(8))) __bf16 bf16x8;
typedef __attribute__((ext_vector_type(4))) float f32x4;
typedef __attribute__((ext_vector_type(4))) unsigned short us4;

__device__ __forceinline__ unsigned short f2bf(float f) {
    unsigned u = __float_as_uint(f);
    return (unsigned short)((u + 0x7FFFu + ((u >> 16) & 1u)) >> 16);
}
__device__ __forceinline__ float bflo(unsigned w) {
    return __uint_as_float(w << 16);
}
__device__ __forceinline__ float bfhi(unsigned w) {
    return __uint_as_float(w & 0xffff0000u);
}

template <int CTRL>
__device__ __forceinline__ float dpp_add(float v) {
    return v + __int_as_float(__builtin_amdgcn_update_dpp(
                   0, __float_as_int(v), CTRL, 0xF, 0xF, true));
}
// sum over 16 lanes of a DPP row; valid at (lane&15)==15 (row_shr -> high lane)
__device__ __forceinline__ float row_reduce16(float v) {
    v = dpp_add<0x118>(v);
    v = dpp_add<0x114>(v);
    v = dpp_add<0x112>(v);
    v = dpp_add<0x111>(v);
    return v;
}

// ---------------- prep: W1 swizzle, Wut/Wvt bf16-swizzled, bu/bv/w4p ------
__global__ void prep1(const float* __restrict__ W1, const float* __restrict__ W2,
                      const float* __restrict__ W3, const float* __restrict__ b2,
                      const float* __restrict__ b3, const float* __restrict__ W4,
                      const void* __restrict__ eidx,
                      unsigned short* __restrict__ w1s,
                      unsigned short* __restrict__ wuts,
                      unsigned short* __restrict__ wvts, float* __restrict__ bu,
                      float* __restrict__ bv, float* __restrict__ w4p,
                      int* __restrict__ flag) {
    int t = blockIdx.x * blockDim.x + threadIdx.x;  // 131072 threads
    if (t < 32768) {  // W1 swizzle: K=128, N=256, [k/8][n][k%8]
        int k = t >> 8, n = t & 255;
        w1s[(k >> 3) * 2048 + n * 8 + (k & 7)] = f2bf(W1[t]);
    }
    if (t < 65536) {  // Wut[k][n] = sum_j W2[k][j] * W3[j][n], j<128
        int k = t >> 8, n = t & 255;
        float s = 0.0f;
        for (int j = 0; j < 128; ++j) s += W2[k * 128 + j] * W3[j * 256 + n];
        wuts[(k >> 3) * 2048 + n * 8 + (k & 7)] = f2bf(s);
    } else {          // Wvt[k][n] = sum_j W2[k][j] * W3[128+j][n]
        int i = t - 65536;
        int k = i >> 8, n = i & 255;
        float s = 0.0f;
        for (int j = 0; j < 128; ++j) s += W2[k * 128 + j] * W3[(128 + j) * 256 + n];
        wvts[(k >> 3) * 2048 + n * 8 + (k & 7)] = f2bf(s);
    }
    if (t < 256) {    // bu = b3 + b2 @ W3t
        float s = b3[t];
        for (int j = 0; j < 128; ++j) s += b2[j] * W3[j * 256 + t];
        bu[t] = s;
    } else if (t < 512) {  // bv = b2 @ W3b
        int n = t - 256;
        float s = 0.0f;
        for (int j = 0; j < 128; ++j) s += b2[j] * W3[(128 + j) * 256 + n];
        bv[n] = s;
    } else if (t < 768) {  // permuted W4: phys p -> hidden index
        int p = t - 512;
        int wq = p >> 6, local = p & 63;
        w4p[p] = W4[wq * 64 + (local & 3) * 16 + ((local >> 2) & 15)];
    }
    if (t == 0) {
        const unsigned* u = (const unsigned*)eidx;
        int all0 = 1;
        for (int i = 0; i < 32; ++i) all0 &= (u[2 * i + 1] == 0u);
        *flag = all0;
    }
}

// ---------------- node_uv: x -> relu1 -> U,V; coalesced permuted stores ---
__global__ __launch_bounds__(256, 3) void node_uv(
    const float* __restrict__ x, const float* __restrict__ b1,
    const unsigned short* __restrict__ w1s, const unsigned short* __restrict__ wuts,
    const unsigned short* __restrict__ wvts, const float* __restrict__ bu,
    const float* __restrict__ bv, unsigned short* __restrict__ Ug,
    unsigned short* __restrict__ Vg) {
    __shared__ __align__(16) unsigned short A1[64 * 136];  // 17408 B
    __shared__ __align__(16) unsigned short A2[64 * 264];  // 33792 B

    const int t = threadIdx.x, lane = t & 63, w = t >> 6;  // w: 0..3
    const int cl = lane & 15, q = lane >> 4;
    const int nb = w * 64;   // this wave's 64 N-cols
    const int m0 = blockIdx.x * 64;

    // stage x -> A1 bf16
    {
        const float4* x4 = (const float4*)x;
#pragma unroll
        for (int i = 0; i < 8; ++i) {
            int lin = i * 256 + t;
            int m = lin >> 5, c = lin & 31;
            int node = m0 + m;
            if (node > NN - 1) node = NN - 1;
            float4 v = x4[node * 32 + c];
            us4 b;
            b.x = f2bf(v.x); b.y = f2bf(v.y); b.z = f2bf(v.z); b.w = f2bf(v.w);
            *(us4*)(A1 + m * 136 + c * 4) = b;
        }
    }
    float b1v[4], buv[4], bvv[4];
#pragma unroll
    for (int nt = 0; nt < 4; ++nt) {
        int n = nb + nt * 16 + cl;
        b1v[nt] = b1[n];
        buv[nt] = bu[n];
        bvv[nt] = bv[n];
    }
    __syncthreads();

    // GEMM1: [64x128]x[128x256], B streamed from L2
    {
        f32x4 acc[4][4];
#pragma unroll
        for (int mt = 0; mt < 4; ++mt)
#pragma unroll
            for (int nt = 0; nt < 4; ++nt)
                acc[mt][nt] = (f32x4){b1v[nt], b1v[nt], b1v[nt], b1v[nt]};
#pragma unroll
        for (int s = 0; s < 4; ++s) {
            bf16x8 a[4], bw[4];
#pragma unroll
            for (int mt = 0; mt < 4; ++mt)
                a[mt] = *(const bf16x8*)(A1 + (mt * 16 + cl) * 136 + s * 32 + q * 8);
#pragma unroll
            for (int nt = 0; nt < 4; ++nt)
                bw[nt] = *(const bf16x8*)(w1s + (s * 4 + q) * 2048 +
                                          (nb + nt * 16 + cl) * 8);
#pragma unroll
            for (int mt = 0; mt < 4; ++mt)
#pragma unroll
                for (int nt = 0; nt < 4; ++nt)
                    acc[mt][nt] = __builtin_amdgcn_mfma_f32_16x16x32_bf16(
                        a[mt], bw[nt], acc[mt][nt], 0, 0, 0);
        }
        // relu -> A2
#pragma unroll
        for (int mt = 0; mt < 4; ++mt)
#pragma unroll
            for (int nt = 0; nt < 4; ++nt)
#pragma unroll
                for (int r = 0; r < 4; ++r) {
                    float v = fmaxf(acc[mt][nt][r], 0.0f);
                    A2[(mt * 16 + q * 4 + r) * 264 + nb + nt * 16 + cl] = f2bf(v);
                }
    }
    __syncthreads();

    // GEMM U then V (A2 reused); permuted ushort4 epilogue (coalesced)
#pragma unroll
    for (int pass = 0; pass < 2; ++pass) {
        const unsigned short* wt = pass ? wvts : wuts;
        unsigned short* outg = pass ? Vg : Ug;
        f32x4 acc[4][4];
#pragma unroll
        for (int mt = 0; mt < 4; ++mt)
#pragma unroll
            for (int nt = 0; nt < 4; ++nt) {
                float bb = pass ? bvv[nt] : buv[nt];
                acc[mt][nt] = (f32x4){bb, bb, bb, bb};
            }
#pragma unroll
        for (int s = 0; s < 8; ++s) {
            bf16x8 a[4], bw[4];
#pragma unroll
            for (int mt = 0; mt < 4; ++mt)
                a[mt] = *(const bf16x8*)(A2 + (mt * 16 + cl) * 264 + s * 32 + q * 8);
#pragma unroll
            for (int nt = 0; nt < 4; ++nt)
                bw[nt] = *(const bf16x8*)(wt + (s * 4 + q) * 2048 +
                                          (nb + nt * 16 + cl) * 8);
#pragma unroll
            for (int mt = 0; mt < 4; ++mt)
#pragma unroll
                for (int nt = 0; nt < 4; ++nt)
                    acc[mt][nt] = __builtin_amdgcn_mfma_f32_16x16x32_bf16(
                        a[mt], bw[nt], acc[mt][nt], 0, 0, 0);
        }
        // store: phys p = nb + cl*4 + nt  (8 B/lane, 4x128B segments/instr)
#pragma unroll
        for (int mt = 0; mt < 4; ++mt)
#pragma unroll
            for (int r = 0; r < 4; ++r) {
                int node = m0 + mt * 16 + q * 4 + r;
                if (node < NN) {
                    us4 v = {f2bf(acc[mt][0][r]), f2bf(acc[mt][1][r]),
                             f2bf(acc[mt][2][r]), f2bf(acc[mt][3][r])};
                    *(us4*)(outg + node * 256 + nb + cl * 4) = v;
                }
            }
    }
}

// ---------------- edge_pred: streaming gather + VALU (permuted W4) --------
#define TERM(uw, vw, wa, wb)                                     \
    (fmaxf(bflo(uw) + bflo(vw), 0.0f) * (wa) +                   \
     fmaxf(bfhi(uw) + bfhi(vw), 0.0f) * (wb))

__global__ __launch_bounds__(256, 8) void edge_pred(
    const void* __restrict__ eidx, const unsigned short* __restrict__ Ut,
    const unsigned short* __restrict__ Vt, const float* __restrict__ w4p,
    const float* __restrict__ b4, const int* __restrict__ flag,
    float* __restrict__ out) {
    const int t = threadIdx.x, lane = t & 63;
    const int cl = lane & 15, g = lane >> 4;   // 4 edge-groups of 16 lanes
    const int gwid = (blockIdx.x * 256 + t) >> 6;
    const int nw = (GRID_EP * 256) >> 6;
    const bool i64f = (*flag != 0);
    const int* ei32 = (const int*)eidx;
    const long long* ei64 = (const long long*)eidx;

    float w4a[8], w4b[8];
#pragma unroll
    for (int j = 0; j < 8; ++j) {
        w4a[j] = w4p[cl * 8 + j];
        w4b[j] = w4p[128 + cl * 8 + j];
    }
    const float b4v = b4[0];

    for (int base = gwid * 8; base < NE; base += nw * 8) {
        const int eA = base + g, eB = base + 4 + g;
        int sA = i64f ? (int)ei64[eA] : ei32[eA];
        int dA = i64f ? (int)ei64[NE + eA] : ei32[NE + eA];
        int sB = i64f ? (int)ei64[eB] : ei32[eB];
        int dB = i64f ? (int)ei64[NE + eB] : ei32[NE + eB];
        sA = sA < 0 ? 0 : (sA > NN - 1 ? NN - 1 : sA);
        dA = dA < 0 ? 0 : (dA > NN - 1 ? NN - 1 : dA);
        sB = sB < 0 ? 0 : (sB > NN - 1 ? NN - 1 : sB);
        dB = dB < 0 ? 0 : (dB > NN - 1 ? NN - 1 : dB);

        const uint4* ua = (const uint4*)(Ut + (long)sA * 256) + cl;
        const uint4* va = (const uint4*)(Vt + (long)dA * 256) + cl;
        const uint4* ub = (const uint4*)(Ut + (long)sB * 256) + cl;
        const uint4* vb = (const uint4*)(Vt + (long)dB * 256) + cl;
        uint4 ua0 = ua[0], ua1 = ua[16];
        uint4 va0 = va[0], va1 = va[16];
        uint4 ub0 = ub[0], ub1 = ub[16];
        uint4 vb0 = vb[0], vb1 = vb[16];

        float accA =
            TERM(ua0.x, va0.x, w4a[0], w4a[1]) + TERM(ua0.y, va0.y, w4a[2], w4a[3]) +
            TERM(ua0.z, va0.z, w4a[4], w4a[5]) + TERM(ua0.w, va0.w, w4a[6], w4a[7]) +
            TERM(ua1.x, va1.x, w4b[0], w4b[1]) + TERM(ua1.y, va1.y, w4b[2], w4b[3]) +
            TERM(ua1.z, va1.z, w4b[4], w4b[5]) + TERM(ua1.w, va1.w, w4b[6], w4b[7]);
        float accB =
            TERM(ub0.x, vb0.x, w4a[0], w4a[1]) + TERM(ub0.y, vb0.y, w4a[2], w4a[3]) +
            TERM(ub0.z, vb0.z, w4a[4], w4a[5]) + TERM(ub0.w, vb0.w, w4a[6], w4a[7]) +
            TERM(ub1.x, vb1.x, w4b[0], w4b[1]) + TERM(ub1.y, vb1.y, w4b[2], w4b[3]) +
            TERM(ub1.z, vb1.z, w4b[4], w4b[5]) + TERM(ub1.w, vb1.w, w4b[6], w4b[7]);

        accA = row_reduce16(accA);
        accB = row_reduce16(accB);
        if (cl == 15) {
            out[eA] = 1.0f / (1.0f + __expf(-(accA + b4v)));
            out[eB] = 1.0f / (1.0f + __expf(-(accB + b4v)));
        }
    }
}

extern "C" void kernel_launch(void* const* d_in, const int* in_sizes, int n_in,
                              void* d_out, int out_size, void* d_ws, size_t ws_size,
                              hipStream_t stream) {
    const float* x  = (const float*)d_in[0];
    const void*  ei = d_in[1];
    const float* W1 = (const float*)d_in[2];
    const float* b1 = (const float*)d_in[3];
    const float* W2 = (const float*)d_in[4];
    const float* b2 = (const float*)d_in[5];
    const float* W3 = (const float*)d_in[6];
    const float* b3 = (const float*)d_in[7];
    const float* W4 = (const float*)d_in[8];
    const float* b4 = (const float*)d_in[9];

    char* ws = (char*)d_ws;
    int* flag            = (int*)ws;
    unsigned short* w1s  = (unsigned short*)(ws + 256);
    unsigned short* wuts = (unsigned short*)(ws + 65792);
    unsigned short* wvts = (unsigned short*)(ws + 196864);
    float* bu            = (float*)(ws + 327936);
    float* bv            = (float*)(ws + 328960);
    float* w4p           = (float*)(ws + 329984);
    unsigned short* Ug   = (unsigned short*)(ws + 1048576);
    unsigned short* Vg   = (unsigned short*)(ws + 52248576);

    prep1<<<512, 256, 0, stream>>>(W1, W2, W3, b2, b3, W4, ei, w1s, wuts, wvts,
                                   bu, bv, w4p, flag);
    node_uv<<<NTN, 256, 0, stream>>>(x, b1, w1s, wuts, wvts, bu, bv, Ug, Vg);
    edge_pred<<<GRID_EP, 256, 0, stream>>>(ei, Ug, Vg, w4p, b4, flag, (float*)d_out);
}